// Round 1
// baseline (38252.652 us; speedup 1.0000x reference)
//
#include <hip/hip_runtime.h>
#include <cstddef>

#define HD 33
#define G4 132            // 4*HD gate rows
#define TLEN 100000
#define NPRED 20
#define CH 16             // mvts timesteps staged per LDS chunk (fused path)
#define NCH (TLEN / CH)   // 6250, exact

// ---- fast elementwise nonlinearities (fp32, NaN-safe at +-inf) ----
__device__ __forceinline__ float sigm(float x) {
  return 1.0f / (1.0f + __expf(-x));
}
__device__ __forceinline__ float tanh_fast(float x) {
  float e = __expf(2.0f * x);          // inf for large x -> 1 - 0 = 1; 0 for very neg -> -1
  return 1.0f - 2.0f / (e + 1.0f);
}

// quad_perm broadcast of lane q within each group of 4 lanes (pure VALU DPP)
template <int CTRL>
__device__ __forceinline__ float qbcast(float v) {
  return __int_as_float(
      __builtin_amdgcn_mov_dpp(__float_as_int(v), CTRL, 0xF, 0xF, true));
}

// ============================================================
// Kernel A: x_proj[t][j] = b_ih1[j] + b_hh1[j] + sum_k mvts[t][k] * W_ih1[j][k]
// grid = NCH blocks, block = 132 threads (thread j owns gate row j)
// ============================================================
__global__ void xproj_kernel(const float* __restrict__ mvts,
                             const float* __restrict__ W_ih1,
                             const float* __restrict__ b_ih1,
                             const float* __restrict__ b_hh1,
                             float* __restrict__ xp) {
  __shared__ __align__(16) float4 mt4[CH * HD / 4];  // 528 floats = 132 float4
  const int tid = threadIdx.x;                        // 0..131
  const int t0 = blockIdx.x * CH;

  float w[HD];
#pragma unroll
  for (int k = 0; k < HD; ++k) w[k] = W_ih1[tid * HD + k];
  const float b = b_ih1[tid] + b_hh1[tid];

  mt4[tid] = reinterpret_cast<const float4*>(mvts + (size_t)t0 * HD)[tid];
  __syncthreads();
  const float* mt = reinterpret_cast<const float*>(mt4);

#pragma unroll 4
  for (int tt = 0; tt < CH; ++tt) {
    const float* r = mt + tt * HD;
    float a0 = 0.f, a1 = 0.f, a2 = 0.f, a3 = 0.f;
#pragma unroll
    for (int k = 0; k < 32; k += 4) {
      a0 += w[k] * r[k];
      a1 += w[k + 1] * r[k + 1];
      a2 += w[k + 2] * r[k + 2];
      a3 += w[k + 3] * r[k + 3];
    }
    a0 += w[32] * r[32];
    xp[(size_t)(t0 + tt) * G4 + tid] = b + ((a0 + a1) + (a2 + a3));
  }
}

// ============================================================
// Kernel B: sequential scan (1 block, 132 threads = 33 units x 4 gates)
//   thread 4u+p computes gate row j = p*HD+u  (p: 0=i 1=f 2=g 3=o)
//   h broadcast via double-buffered LDS (1 barrier/step)
//   i/f/g/o exchange via DPP quad broadcast (lanes 4u..4u+3 share a quad)
// FUSED=true computes the input projection on the fly (no workspace needed).
// ============================================================
template <bool FUSED>
__global__ void lstm_scan(const float* __restrict__ mvts,
                          const float* __restrict__ xp,
                          const float* __restrict__ W_ih1,
                          const float* __restrict__ W_hh1,
                          const float* __restrict__ b_ih1,
                          const float* __restrict__ b_hh1,
                          const float* __restrict__ W_ih2,
                          const float* __restrict__ b_ih2,
                          const float* __restrict__ b_hh2,
                          float* __restrict__ out) {
  __shared__ __align__(16) float hbuf[2][36];        // rows padded to 16B multiple
  __shared__ __align__(16) float4 mt4[2][CH * HD / 4];  // fused-path mvts tiles

  const int tid = threadIdx.x;  // 0..131
  const int u = tid >> 2;       // hidden unit 0..32
  const int p = tid & 3;        // gate part
  const int j = p * HD + u;     // gate row

  float whh[HD];
#pragma unroll
  for (int k = 0; k < HD; ++k) whh[k] = W_hh1[j * HD + k];

  float wih[FUSED ? HD : 1];
  float bv = 0.f;
  if constexpr (FUSED) {
#pragma unroll
    for (int k = 0; k < HD; ++k) wih[k] = W_ih1[j * HD + k];
    bv = b_ih1[j] + b_hh1[j];
  }

  if (tid < HD) hbuf[0][tid] = 0.f;

  // prefetch state
  float xpf0, xpf1, xpf2, xpf3;   // precomputed-xp pipeline (depth 4)
  float4 pfreg;                   // fused-path next-chunk staging register
  if constexpr (!FUSED) {
    xpf0 = xp[(size_t)0 * G4 + j];
    xpf1 = xp[(size_t)1 * G4 + j];
    xpf2 = xp[(size_t)2 * G4 + j];
    xpf3 = xp[(size_t)3 * G4 + j];
  } else {
    mt4[0][tid] = reinterpret_cast<const float4*>(mvts)[tid];  // chunk 0
  }
  __syncthreads();

  float c = 0.f;
  int cur = 0;
  for (int t = 0; t < TLEN; ++t) {
    float xv;
    if constexpr (!FUSED) {
      xv = xpf0;
      xpf0 = xpf1; xpf1 = xpf2; xpf2 = xpf3;
      xpf3 = xp[(size_t)(t + 4) * G4 + j];  // 4 rows of slack allocated in ws
    } else {
      const int tt = t & (CH - 1);
      const int chn = (t >> 4) + 1;  // next chunk
      if (tt == 0 && chn < NCH)
        pfreg = reinterpret_cast<const float4*>(mvts + (size_t)chn * CH * HD)[tid];
      const float* r = reinterpret_cast<const float*>(mt4[(t >> 4) & 1]) + tt * HD;
      float a0 = 0.f, a1 = 0.f, a2 = 0.f, a3 = 0.f;
#pragma unroll
      for (int k = 0; k < 32; k += 4) {
        a0 += wih[k] * r[k];
        a1 += wih[k + 1] * r[k + 1];
        a2 += wih[k + 2] * r[k + 2];
        a3 += wih[k + 3] * r[k + 3];
      }
      a0 += wih[32] * r[32];
      xv = bv + ((a0 + a1) + (a2 + a3));
      if (tt == CH - 1 && chn < NCH) mt4[chn & 1][tid] = pfreg;
    }

    // recurrent matvec: gate = xv + sum_k W_hh1[j][k] * h[k]
    const float* hs = hbuf[cur];
    float a0 = 0.f, a1 = 0.f, a2 = 0.f, a3 = 0.f;
#pragma unroll
    for (int k = 0; k < 32; k += 4) {
      a0 += whh[k] * hs[k];
      a1 += whh[k + 1] * hs[k + 1];
      a2 += whh[k + 2] * hs[k + 2];
      a3 += whh[k + 3] * hs[k + 3];
    }
    a0 += whh[32] * hs[32];
    const float gate = xv + ((a0 + a1) + (a2 + a3));

    // nonlinearity: p==2 -> tanh(g), else sigmoid (one exp either way)
    const float v = (p == 2) ? tanh_fast(gate) : sigm(gate);

    // exchange i/f/g/o within the lane quad
    const float iv = qbcast<0x00>(v);
    const float fv = qbcast<0x55>(v);
    const float gv = qbcast<0xAA>(v);
    const float ov = qbcast<0xFF>(v);

    c = fv * c + iv * gv;          // replicated identically across the quad
    const float hv = ov * tanh_fast(c);
    if (p == 0) hbuf[cur ^ 1][u] = hv;
    cur ^= 1;
    __syncthreads();
  }

  // ---- decode: 20 steps, no carried state in lstm2 (f-gate * 0 vanishes) ----
  float w2[HD];
#pragma unroll
  for (int k = 0; k < HD; ++k) w2[k] = W_ih2[j * HD + k];
  const float b2v = b_ih2[j] + b_hh2[j];

  for (int s = 0; s < NPRED; ++s) {
    const float* xs = hbuf[cur];
    float a0 = 0.f, a1 = 0.f, a2 = 0.f, a3 = 0.f;
#pragma unroll
    for (int k = 0; k < 32; k += 4) {
      a0 += w2[k] * xs[k];
      a1 += w2[k + 1] * xs[k + 1];
      a2 += w2[k + 2] * xs[k + 2];
      a3 += w2[k + 3] * xs[k + 3];
    }
    a0 += w2[32] * xs[32];
    const float gate = b2v + ((a0 + a1) + (a2 + a3));
    const float v = (p == 2) ? tanh_fast(gate) : sigm(gate);
    const float iv = qbcast<0x00>(v);
    const float gv = qbcast<0xAA>(v);
    const float ov = qbcast<0xFF>(v);
    const float c2 = iv * gv;
    const float h2 = ov * tanh_fast(c2);
    if (p == 0) {
      hbuf[cur ^ 1][u] = h2;
      out[s * HD + u] = h2;
    }
    cur ^= 1;
    __syncthreads();
  }
}

// ============================================================
extern "C" void kernel_launch(void* const* d_in, const int* in_sizes, int n_in,
                              void* d_out, int out_size, void* d_ws, size_t ws_size,
                              hipStream_t stream) {
  const float* mvts  = (const float*)d_in[0];
  const float* W_ih1 = (const float*)d_in[1];
  const float* W_hh1 = (const float*)d_in[2];
  const float* b_ih1 = (const float*)d_in[3];
  const float* b_hh1 = (const float*)d_in[4];
  const float* W_ih2 = (const float*)d_in[5];
  // d_in[6] = W_hh2: unused (decode always starts from h=c=0)
  const float* b_ih2 = (const float*)d_in[7];
  const float* b_hh2 = (const float*)d_in[8];
  float* out = (float*)d_out;

  const size_t need = (size_t)(TLEN + 4) * G4 * sizeof(float);  // +4 rows slack for prefetch
  if (ws_size >= need) {
    float* xp = (float*)d_ws;
    xproj_kernel<<<NCH, G4, 0, stream>>>(mvts, W_ih1, b_ih1, b_hh1, xp);
    lstm_scan<false><<<1, G4, 0, stream>>>(mvts, xp, W_ih1, W_hh1, b_ih1, b_hh1,
                                           W_ih2, b_ih2, b_hh2, out);
  } else {
    lstm_scan<true><<<1, G4, 0, stream>>>(mvts, nullptr, W_ih1, W_hh1, b_ih1, b_hh1,
                                          W_ih2, b_ih2, b_hh2, out);
  }
}

// Round 2
// 37585.876 us; speedup vs baseline: 1.0177x; 1.0177x over previous
//
#include <hip/hip_runtime.h>
#include <cstddef>

#define HD 33
#define G4 132            // 4*HD gate rows
#define TLEN 100000
#define NPRED 20
#define CH 16             // mvts timesteps staged per LDS chunk (fused path)
#define NCH (TLEN / CH)   // 6250, exact
#define PF 8              // x_proj register prefetch depth

// ---- fast elementwise nonlinearities (fp32, NaN-safe at +-inf) ----
__device__ __forceinline__ float sigm(float x) {
  return 1.0f / (1.0f + __expf(-x));
}
__device__ __forceinline__ float tanh_fast(float x) {
  float e = __expf(2.0f * x);          // inf for large x -> 1; 0 for very neg -> -1
  return 1.0f - 2.0f / (e + 1.0f);
}

// quad_perm broadcast of lane q within each group of 4 lanes (pure VALU DPP)
template <int CTRL>
__device__ __forceinline__ float qbcast(float v) {
  return __int_as_float(
      __builtin_amdgcn_mov_dpp(__float_as_int(v), CTRL, 0xF, 0xF, true));
}

// ============================================================
// Kernel A: x_proj[t][j] = b_ih1[j] + b_hh1[j] + sum_k mvts[t][k] * W_ih1[j][k]
// grid = NCH blocks, block = 132 threads (thread j owns gate row j)
// ============================================================
__global__ void __launch_bounds__(G4, 1)
xproj_kernel(const float* __restrict__ mvts,
             const float* __restrict__ W_ih1,
             const float* __restrict__ b_ih1,
             const float* __restrict__ b_hh1,
             float* __restrict__ xp) {
  __shared__ __align__(16) float4 mt4[CH * HD / 4];  // 528 floats = 132 float4
  const int tid = threadIdx.x;                        // 0..131
  const int t0 = blockIdx.x * CH;

  float w[HD];
#pragma unroll
  for (int k = 0; k < HD; ++k) w[k] = W_ih1[tid * HD + k];
  const float b = b_ih1[tid] + b_hh1[tid];

  mt4[tid] = reinterpret_cast<const float4*>(mvts + (size_t)t0 * HD)[tid];
  __syncthreads();
  const float* mt = reinterpret_cast<const float*>(mt4);

#pragma unroll 4
  for (int tt = 0; tt < CH; ++tt) {
    const float* r = mt + tt * HD;
    float a0 = 0.f, a1 = 0.f, a2 = 0.f, a3 = 0.f;
#pragma unroll
    for (int k = 0; k < 32; k += 4) {
      a0 += w[k] * r[k];
      a1 += w[k + 1] * r[k + 1];
      a2 += w[k + 2] * r[k + 2];
      a3 += w[k + 3] * r[k + 3];
    }
    a0 += w[32] * r[32];
    xp[(size_t)(t0 + tt) * G4 + tid] = b + ((a0 + a1) + (a2 + a3));
  }
}

// ============================================================
// Kernel B: sequential scan (1 block, 132 threads = 33 units x 4 gates)
//   thread 4u+p computes gate row j = p*HD+u  (p: 0=i 1=f 2=g 3=o)
//   h broadcast via double-buffered LDS (1 barrier/step)
//   i/f/g/o exchange via DPP quad broadcast (lanes 4u..4u+3 share a quad)
// FUSED=true computes the input projection on the fly (no workspace needed).
// ============================================================
template <bool FUSED>
__global__ void __launch_bounds__(G4, 1)
lstm_scan(const float* __restrict__ mvts,
          const float* __restrict__ xp,
          const float* __restrict__ W_ih1,
          const float* __restrict__ W_hh1,
          const float* __restrict__ b_ih1,
          const float* __restrict__ b_hh1,
          const float* __restrict__ W_ih2,
          const float* __restrict__ b_ih2,
          const float* __restrict__ b_hh2,
          float* __restrict__ out) {
  __shared__ __align__(16) float hbuf[2][36];           // 144 B rows (16B-aligned)
  __shared__ __align__(16) float4 mt4[2][CH * HD / 4];  // fused-path mvts tiles

  const int tid = threadIdx.x;  // 0..131
  const int u = tid >> 2;       // hidden unit 0..32
  const int p = tid & 3;        // gate part
  const int j = p * HD + u;     // gate row

  float whh[HD];
#pragma unroll
  for (int k = 0; k < HD; ++k) whh[k] = W_hh1[j * HD + k];

  float wih[FUSED ? HD : 1];
  float bv = 0.f;
  if constexpr (FUSED) {
#pragma unroll
    for (int k = 0; k < HD; ++k) wih[k] = W_ih1[j * HD + k];
    bv = b_ih1[j] + b_hh1[j];
  }

  if (tid < HD) {
    hbuf[0][tid] = 0.f;
    hbuf[1][tid] = 0.f;
  }

  // prefetch state
  float xpf[PF];                  // precomputed-xp register pipeline
  float4 pfreg;                   // fused-path next-chunk staging register
  if constexpr (!FUSED) {
#pragma unroll
    for (int q = 0; q < PF; ++q) xpf[q] = xp[(size_t)q * G4 + j];
  } else {
    mt4[0][tid] = reinterpret_cast<const float4*>(mvts)[tid];  // chunk 0
  }
  __syncthreads();

  float c = 0.f;
  int cur = 0;
  for (int t = 0; t < TLEN; ++t) {
    float xv;
    if constexpr (!FUSED) {
      xv = xpf[0];
#pragma unroll
      for (int q = 0; q < PF - 1; ++q) xpf[q] = xpf[q + 1];
      xpf[PF - 1] = xp[(size_t)(t + PF) * G4 + j];  // PF rows of slack in ws
    } else {
      const int tt = t & (CH - 1);
      const int chn = (t >> 4) + 1;  // next chunk
      if (tt == 0 && chn < NCH)
        pfreg = reinterpret_cast<const float4*>(mvts + (size_t)chn * CH * HD)[tid];
      const float* r = reinterpret_cast<const float*>(mt4[(t >> 4) & 1]) + tt * HD;
      float a0 = 0.f, a1 = 0.f, a2 = 0.f, a3 = 0.f;
#pragma unroll
      for (int k = 0; k < 32; k += 4) {
        a0 += wih[k] * r[k];
        a1 += wih[k + 1] * r[k + 1];
        a2 += wih[k + 2] * r[k + 2];
        a3 += wih[k + 3] * r[k + 3];
      }
      a0 += wih[32] * r[32];
      xv = bv + ((a0 + a1) + (a2 + a3));
      if (tt == CH - 1 && chn < NCH) mt4[chn & 1][tid] = pfreg;
    }

    // recurrent matvec: gate = xv + sum_k W_hh1[j][k] * h[k]
    // h read as 8x float4 + 1 scalar (broadcast across lanes, conflict-free)
    const float4* h4 = reinterpret_cast<const float4*>(hbuf[cur]);
    float a0 = 0.f, a1 = 0.f, a2 = 0.f, a3 = 0.f;
#pragma unroll
    for (int q = 0; q < 8; ++q) {
      const float4 hq = h4[q];
      a0 += whh[4 * q] * hq.x;
      a1 += whh[4 * q + 1] * hq.y;
      a2 += whh[4 * q + 2] * hq.z;
      a3 += whh[4 * q + 3] * hq.w;
    }
    a0 += whh[32] * hbuf[cur][32];
    const float gate = xv + ((a0 + a1) + (a2 + a3));

    // nonlinearity: p==2 -> tanh(g), else sigmoid (one exp either way)
    const float v = (p == 2) ? tanh_fast(gate) : sigm(gate);

    // exchange i/f/g/o within the lane quad
    const float iv = qbcast<0x00>(v);
    const float fv = qbcast<0x55>(v);
    const float gv = qbcast<0xAA>(v);
    const float ov = qbcast<0xFF>(v);

    c = fv * c + iv * gv;          // replicated identically across the quad
    const float hv = ov * tanh_fast(c);
    if (p == 0) hbuf[cur ^ 1][u] = hv;
    cur ^= 1;
    __syncthreads();
  }

  // ---- decode: 20 steps, no carried state in lstm2 (f-gate * 0 vanishes) ----
  float w2[HD];
#pragma unroll
  for (int k = 0; k < HD; ++k) w2[k] = W_ih2[j * HD + k];
  const float b2v = b_ih2[j] + b_hh2[j];

  for (int s = 0; s < NPRED; ++s) {
    const float* xs = hbuf[cur];
    float a0 = 0.f, a1 = 0.f, a2 = 0.f, a3 = 0.f;
#pragma unroll
    for (int k = 0; k < 32; k += 4) {
      a0 += w2[k] * xs[k];
      a1 += w2[k + 1] * xs[k + 1];
      a2 += w2[k + 2] * xs[k + 2];
      a3 += w2[k + 3] * xs[k + 3];
    }
    a0 += w2[32] * xs[32];
    const float gate = b2v + ((a0 + a1) + (a2 + a3));
    const float v = (p == 2) ? tanh_fast(gate) : sigm(gate);
    const float iv = qbcast<0x00>(v);
    const float gv = qbcast<0xAA>(v);
    const float ov = qbcast<0xFF>(v);
    const float c2 = iv * gv;
    const float h2 = ov * tanh_fast(c2);
    if (p == 0) {
      hbuf[cur ^ 1][u] = h2;
      out[s * HD + u] = h2;
    }
    cur ^= 1;
    __syncthreads();
  }
}

// ============================================================
extern "C" void kernel_launch(void* const* d_in, const int* in_sizes, int n_in,
                              void* d_out, int out_size, void* d_ws, size_t ws_size,
                              hipStream_t stream) {
  const float* mvts  = (const float*)d_in[0];
  const float* W_ih1 = (const float*)d_in[1];
  const float* W_hh1 = (const float*)d_in[2];
  const float* b_ih1 = (const float*)d_in[3];
  const float* b_hh1 = (const float*)d_in[4];
  const float* W_ih2 = (const float*)d_in[5];
  // d_in[6] = W_hh2: unused (decode always starts from h=c=0)
  const float* b_ih2 = (const float*)d_in[7];
  const float* b_hh2 = (const float*)d_in[8];
  float* out = (float*)d_out;

  const size_t need = (size_t)(TLEN + PF) * G4 * sizeof(float);  // +PF rows slack
  if (ws_size >= need) {
    float* xp = (float*)d_ws;
    xproj_kernel<<<NCH, G4, 0, stream>>>(mvts, W_ih1, b_ih1, b_hh1, xp);
    lstm_scan<false><<<1, G4, 0, stream>>>(mvts, xp, W_ih1, W_hh1, b_ih1, b_hh1,
                                           W_ih2, b_ih2, b_hh2, out);
  } else {
    lstm_scan<true><<<1, G4, 0, stream>>>(mvts, nullptr, W_ih1, W_hh1, b_ih1, b_hh1,
                                          W_ih2, b_ih2, b_hh2, out);
  }
}

// Round 3
// 35290.533 us; speedup vs baseline: 1.0839x; 1.0650x over previous
//
#include <hip/hip_runtime.h>
#include <cstddef>

#define HD 33
#define G4 132            // 4*HD gate rows
#define TLEN 100000
#define NPRED 20
#define CH 16             // mvts timesteps per xproj block
#define NCH (TLEN / CH)   // 6250, exact
#define TPAD (TLEN + 16)  // xp row length w/ slack for float4 prefetch

// ---- fast elementwise nonlinearities (fp32, NaN-safe at +-inf) ----
__device__ __forceinline__ float sigm(float x) {
  return 1.0f / (1.0f + __expf(-x));
}
__device__ __forceinline__ float tanh_fast(float x) {
  float e = __expf(2.0f * x);          // inf for large x -> 1; 0 for very neg -> -1
  return 1.0f - 2.0f / (e + 1.0f);
}

// quad_perm broadcast of lane q within each group of 4 lanes (pure VALU DPP)
template <int CTRL>
__device__ __forceinline__ float qbcast(float v) {
  return __int_as_float(
      __builtin_amdgcn_mov_dpp(__float_as_int(v), CTRL, 0xF, 0xF, true));
}

// LDS-only barrier: drains lgkmcnt (LDS) but leaves global loads in flight.
// __syncthreads() would emit s_waitcnt vmcnt(0) and drain the xp prefetch
// pipeline every step (the round-1/2 bottleneck). "memory" clobber keeps the
// compiler from moving LDS ops or sinking loop-invariant loads across it.
#define LGKM_BARRIER() asm volatile("s_waitcnt lgkmcnt(0)\n\ts_barrier" ::: "memory")

// ============================================================
// Kernel A: xpt[j][t] = b_ih1[j] + b_hh1[j] + sum_k mvts[t][k] * W_ih1[j][k]
// TRANSPOSED output layout [G4][TPAD]: scan thread j streams its own row.
// grid = NCH blocks, block = 132 threads (thread j owns gate row j)
// ============================================================
__global__ void __launch_bounds__(G4, 1)
xproj_kernel(const float* __restrict__ mvts,
             const float* __restrict__ W_ih1,
             const float* __restrict__ b_ih1,
             const float* __restrict__ b_hh1,
             float* __restrict__ xpt) {
  __shared__ __align__(16) float4 mt4[CH * HD / 4];  // 528 floats = 132 float4
  const int tid = threadIdx.x;                        // 0..131
  const int t0 = blockIdx.x * CH;

  float w[HD];
#pragma unroll
  for (int k = 0; k < HD; ++k) w[k] = W_ih1[tid * HD + k];
  const float b = b_ih1[tid] + b_hh1[tid];

  mt4[tid] = reinterpret_cast<const float4*>(mvts + (size_t)t0 * HD)[tid];
  __syncthreads();
  const float* mt = reinterpret_cast<const float*>(mt4);

  float4* dst = reinterpret_cast<float4*>(xpt + (size_t)tid * TPAD + t0);
#pragma unroll
  for (int g = 0; g < CH / 4; ++g) {
    float4 v;
    float* vp = reinterpret_cast<float*>(&v);
#pragma unroll
    for (int e = 0; e < 4; ++e) {
      const float* r = mt + (4 * g + e) * HD;
      float a0 = 0.f, a1 = 0.f, a2 = 0.f, a3 = 0.f;
#pragma unroll
      for (int k = 0; k < 32; k += 4) {
        a0 += w[k] * r[k];
        a1 += w[k + 1] * r[k + 1];
        a2 += w[k + 2] * r[k + 2];
        a3 += w[k + 3] * r[k + 3];
      }
      a0 += w[32] * r[32];
      vp[e] = b + ((a0 + a1) + (a2 + a3));
    }
    dst[g] = v;                       // 16B store, own row -> own lines
  }
}

// ============================================================
// Kernel B (precomputed path): sequential scan, 1 block, 132 threads.
//   thread 4u+p computes gate row j = p*HD+u  (p: 0=i 1=f 2=g 3=o)
//   h double-buffered in LDS, statically alternating (unroll 4)
//   one LGKM-only barrier per step; xp float4 loads stay in flight
// ============================================================
__global__ void __launch_bounds__(G4, 1)
lstm_scan_pre(const float* __restrict__ xpt,
              const float* __restrict__ W_hh1,
              const float* __restrict__ W_ih2,
              const float* __restrict__ b_ih2,
              const float* __restrict__ b_hh2,
              float* __restrict__ out) {
  __shared__ __align__(16) float hbuf[2][36];  // 144B rows, 16B aligned

  const int tid = threadIdx.x;  // 0..131
  const int u = tid >> 2;       // hidden unit 0..32
  const int p = tid & 3;        // gate part
  const int j = p * HD + u;     // gate row

  float whh[HD];
#pragma unroll
  for (int k = 0; k < HD; ++k) whh[k] = W_hh1[j * HD + k];

  if (tid < HD) {
    hbuf[0][tid] = 0.f;
    hbuf[1][tid] = 0.f;
  }

  // 3-deep float4 pipeline over this thread's private xp row
  const float* xrow = xpt + (size_t)j * TPAD;
  float4 q0 = *reinterpret_cast<const float4*>(xrow + 0);
  float4 q1 = *reinterpret_cast<const float4*>(xrow + 4);
  float4 q2 = *reinterpret_cast<const float4*>(xrow + 8);
  __syncthreads();  // hbuf init visible (one-time full drain is fine)

  float c = 0.f;

#define STEP(XV, RB, WB)                                                   \
  do {                                                                     \
    const float4* h4 = reinterpret_cast<const float4*>(hbuf[RB]);          \
    float a0 = 0.f, a1 = 0.f, a2 = 0.f, a3 = 0.f;                          \
    _Pragma("unroll")                                                      \
    for (int q = 0; q < 8; ++q) {                                          \
      const float4 hq = h4[q];                                             \
      a0 += whh[4 * q] * hq.x;                                             \
      a1 += whh[4 * q + 1] * hq.y;                                         \
      a2 += whh[4 * q + 2] * hq.z;                                         \
      a3 += whh[4 * q + 3] * hq.w;                                         \
    }                                                                      \
    a0 += whh[32] * hbuf[RB][32];                                          \
    const float gate = (XV) + ((a0 + a1) + (a2 + a3));                     \
    const float v = (p == 2) ? tanh_fast(gate) : sigm(gate);               \
    const float iv = qbcast<0x00>(v);                                      \
    const float fv = qbcast<0x55>(v);                                      \
    const float gv = qbcast<0xAA>(v);                                      \
    const float ov = qbcast<0xFF>(v);                                      \
    c = fv * c + iv * gv;                                                  \
    const float hv = ov * tanh_fast(c);                                    \
    if (p == 0) hbuf[WB][u] = hv;                                          \
    LGKM_BARRIER();                                                        \
  } while (0)

  for (int g = 0; g < TLEN / 4; ++g) {  // 25000 groups of 4 steps
    // prefetch for group g+3 (12 steps ahead); stays in flight across barriers
    const float4 qn = *reinterpret_cast<const float4*>(xrow + 4 * g + 12);
    STEP(q0.x, 0, 1);
    STEP(q0.y, 1, 0);
    STEP(q0.z, 0, 1);
    STEP(q0.w, 1, 0);
    q0 = q1; q1 = q2; q2 = qn;
  }
#undef STEP
  // TLEN % 4 == 0 -> final h lives in hbuf[0]

  // ---- decode: 20 steps, lstm2 has no carried state (h=c=0 each step) ----
  float w2[HD];
#pragma unroll
  for (int k = 0; k < HD; ++k) w2[k] = W_ih2[j * HD + k];
  const float b2v = b_ih2[j] + b_hh2[j];

  int cur = 0;
  for (int s = 0; s < NPRED; ++s) {
    const float* xs = hbuf[cur];
    float a0 = 0.f, a1 = 0.f, a2 = 0.f, a3 = 0.f;
#pragma unroll
    for (int k = 0; k < 32; k += 4) {
      a0 += w2[k] * xs[k];
      a1 += w2[k + 1] * xs[k + 1];
      a2 += w2[k + 2] * xs[k + 2];
      a3 += w2[k + 3] * xs[k + 3];
    }
    a0 += w2[32] * xs[32];
    const float gate = b2v + ((a0 + a1) + (a2 + a3));
    const float v = (p == 2) ? tanh_fast(gate) : sigm(gate);
    const float iv = qbcast<0x00>(v);
    const float gv = qbcast<0xAA>(v);
    const float ov = qbcast<0xFF>(v);
    const float c2 = iv * gv;
    const float h2 = ov * tanh_fast(c2);
    if (p == 0) {
      hbuf[cur ^ 1][u] = h2;
      out[s * HD + u] = h2;
    }
    cur ^= 1;
    __syncthreads();
  }
}

// ============================================================
// Fallback (no workspace): fused input projection, round-2 structure.
// ============================================================
__global__ void __launch_bounds__(G4, 1)
lstm_scan_fused(const float* __restrict__ mvts,
                const float* __restrict__ W_ih1,
                const float* __restrict__ W_hh1,
                const float* __restrict__ b_ih1,
                const float* __restrict__ b_hh1,
                const float* __restrict__ W_ih2,
                const float* __restrict__ b_ih2,
                const float* __restrict__ b_hh2,
                float* __restrict__ out) {
  __shared__ __align__(16) float hbuf[2][36];
  __shared__ __align__(16) float4 mt4[2][CH * HD / 4];

  const int tid = threadIdx.x;
  const int u = tid >> 2;
  const int p = tid & 3;
  const int j = p * HD + u;

  float whh[HD], wih[HD];
#pragma unroll
  for (int k = 0; k < HD; ++k) whh[k] = W_hh1[j * HD + k];
#pragma unroll
  for (int k = 0; k < HD; ++k) wih[k] = W_ih1[j * HD + k];
  const float bv = b_ih1[j] + b_hh1[j];

  if (tid < HD) {
    hbuf[0][tid] = 0.f;
    hbuf[1][tid] = 0.f;
  }
  mt4[0][tid] = reinterpret_cast<const float4*>(mvts)[tid];
  __syncthreads();

  float c = 0.f;
  int cur = 0;
  float4 pfreg;
  for (int t = 0; t < TLEN; ++t) {
    const int tt = t & (CH - 1);
    const int chn = (t >> 4) + 1;
    if (tt == 0 && chn < NCH)
      pfreg = reinterpret_cast<const float4*>(mvts + (size_t)chn * CH * HD)[tid];
    const float* r = reinterpret_cast<const float*>(mt4[(t >> 4) & 1]) + tt * HD;
    float a0 = 0.f, a1 = 0.f, a2 = 0.f, a3 = 0.f;
#pragma unroll
    for (int k = 0; k < 32; k += 4) {
      a0 += wih[k] * r[k];
      a1 += wih[k + 1] * r[k + 1];
      a2 += wih[k + 2] * r[k + 2];
      a3 += wih[k + 3] * r[k + 3];
    }
    a0 += wih[32] * r[32];
    float xv = bv + ((a0 + a1) + (a2 + a3));
    if (tt == CH - 1 && chn < NCH) mt4[chn & 1][tid] = pfreg;

    const float* hs = hbuf[cur];
    float b0 = 0.f, b1 = 0.f, b2 = 0.f, b3 = 0.f;
#pragma unroll
    for (int k = 0; k < 32; k += 4) {
      b0 += whh[k] * hs[k];
      b1 += whh[k + 1] * hs[k + 1];
      b2 += whh[k + 2] * hs[k + 2];
      b3 += whh[k + 3] * hs[k + 3];
    }
    b0 += whh[32] * hs[32];
    const float gate = xv + ((b0 + b1) + (b2 + b3));
    const float v = (p == 2) ? tanh_fast(gate) : sigm(gate);
    const float iv = qbcast<0x00>(v);
    const float fv = qbcast<0x55>(v);
    const float gv = qbcast<0xAA>(v);
    const float ov = qbcast<0xFF>(v);
    c = fv * c + iv * gv;
    const float hv = ov * tanh_fast(c);
    if (p == 0) hbuf[cur ^ 1][u] = hv;
    cur ^= 1;
    __syncthreads();
  }

  float w2[HD];
#pragma unroll
  for (int k = 0; k < HD; ++k) w2[k] = W_ih2[j * HD + k];
  const float b2v = b_ih2[j] + b_hh2[j];

  for (int s = 0; s < NPRED; ++s) {
    const float* xs = hbuf[cur];
    float a0 = 0.f, a1 = 0.f, a2 = 0.f, a3 = 0.f;
#pragma unroll
    for (int k = 0; k < 32; k += 4) {
      a0 += w2[k] * xs[k];
      a1 += w2[k + 1] * xs[k + 1];
      a2 += w2[k + 2] * xs[k + 2];
      a3 += w2[k + 3] * xs[k + 3];
    }
    a0 += w2[32] * xs[32];
    const float gate = b2v + ((a0 + a1) + (a2 + a3));
    const float v = (p == 2) ? tanh_fast(gate) : sigm(gate);
    const float iv = qbcast<0x00>(v);
    const float gv = qbcast<0xAA>(v);
    const float ov = qbcast<0xFF>(v);
    const float c2 = iv * gv;
    const float h2 = ov * tanh_fast(c2);
    if (p == 0) {
      hbuf[cur ^ 1][u] = h2;
      out[s * HD + u] = h2;
    }
    cur ^= 1;
    __syncthreads();
  }
}

// ============================================================
extern "C" void kernel_launch(void* const* d_in, const int* in_sizes, int n_in,
                              void* d_out, int out_size, void* d_ws, size_t ws_size,
                              hipStream_t stream) {
  const float* mvts  = (const float*)d_in[0];
  const float* W_ih1 = (const float*)d_in[1];
  const float* W_hh1 = (const float*)d_in[2];
  const float* b_ih1 = (const float*)d_in[3];
  const float* b_hh1 = (const float*)d_in[4];
  const float* W_ih2 = (const float*)d_in[5];
  // d_in[6] = W_hh2: unused (decode always starts from h=c=0)
  const float* b_ih2 = (const float*)d_in[7];
  const float* b_hh2 = (const float*)d_in[8];
  float* out = (float*)d_out;

  const size_t need = (size_t)G4 * TPAD * sizeof(float);  // ~52.8 MB
  if (ws_size >= need) {
    float* xpt = (float*)d_ws;
    xproj_kernel<<<NCH, G4, 0, stream>>>(mvts, W_ih1, b_ih1, b_hh1, xpt);
    lstm_scan_pre<<<1, G4, 0, stream>>>(xpt, W_hh1, W_ih2, b_ih2, b_hh2, out);
  } else {
    lstm_scan_fused<<<1, G4, 0, stream>>>(mvts, W_ih1, W_hh1, b_ih1, b_hh1,
                                          W_ih2, b_ih2, b_hh2, out);
  }
}

// Round 4
// 35101.624 us; speedup vs baseline: 1.0898x; 1.0054x over previous
//
#include <hip/hip_runtime.h>
#include <cstddef>

#define HD 33
#define G4 132            // 4*HD gate rows
#define TLEN 100000
#define NPRED 20
#define CH 16             // mvts timesteps per xproj block
#define NCH (TLEN / CH)   // 6250, exact
#define TPAD (TLEN + 16)  // xp row length w/ slack for float4 prefetch

// ---- fast elementwise nonlinearities (fp32, NaN-safe at +-inf) ----
__device__ __forceinline__ float sigm(float x) {
  return 1.0f / (1.0f + __expf(-x));
}
__device__ __forceinline__ float tanh_fast(float x) {
  float e = __expf(2.0f * x);          // inf for large x -> 1; 0 for very neg -> -1
  return 1.0f - 2.0f / (e + 1.0f);
}

// quad_perm broadcast of lane q within each group of 4 lanes (pure VALU DPP)
template <int CTRL>
__device__ __forceinline__ float qbcast(float v) {
  return __int_as_float(
      __builtin_amdgcn_mov_dpp(__float_as_int(v), CTRL, 0xF, 0xF, true));
}

// Pin a value into a VGPR as an opaque asm output: the compiler cannot
// rematerialize it (i.e. cannot sink the originating global load into the
// loop) and must carry it live. This is the fix for rounds 1-3 where
// VGPR_Count=36..40 proved W_hh1 was re-loaded from cache every step on the
// serial critical path.
__device__ __forceinline__ void pin(float& x) { asm("" : "+v"(x)); }

// LDS-only barrier: drains lgkmcnt (LDS) but leaves global loads in flight.
// __syncthreads() would emit s_waitcnt vmcnt(0) and drain the xp prefetch
// pipeline every step.
#define LGKM_BARRIER() asm volatile("s_waitcnt lgkmcnt(0)\n\ts_barrier" ::: "memory")

// ============================================================
// Kernel A: xpt[j][t] = b_ih1[j] + b_hh1[j] + sum_k mvts[t][k] * W_ih1[j][k]
// TRANSPOSED output layout [G4][TPAD]: scan thread j streams its own row.
// grid = NCH blocks, block = 132 threads (thread j owns gate row j)
// ============================================================
__global__ void __launch_bounds__(G4, 1)
xproj_kernel(const float* __restrict__ mvts,
             const float* __restrict__ W_ih1,
             const float* __restrict__ b_ih1,
             const float* __restrict__ b_hh1,
             float* __restrict__ xpt) {
  __shared__ __align__(16) float4 mt4[CH * HD / 4];  // 528 floats = 132 float4
  const int tid = threadIdx.x;                        // 0..131
  const int t0 = blockIdx.x * CH;

  float w[HD];
#pragma unroll
  for (int k = 0; k < HD; ++k) w[k] = W_ih1[tid * HD + k];
  const float b = b_ih1[tid] + b_hh1[tid];

  mt4[tid] = reinterpret_cast<const float4*>(mvts + (size_t)t0 * HD)[tid];
  __syncthreads();
  const float* mt = reinterpret_cast<const float*>(mt4);

  float4* dst = reinterpret_cast<float4*>(xpt + (size_t)tid * TPAD + t0);
#pragma unroll
  for (int g = 0; g < CH / 4; ++g) {
    float4 v;
    float* vp = reinterpret_cast<float*>(&v);
#pragma unroll
    for (int e = 0; e < 4; ++e) {
      const float* r = mt + (4 * g + e) * HD;
      float a0 = 0.f, a1 = 0.f, a2 = 0.f, a3 = 0.f;
#pragma unroll
      for (int k = 0; k < 32; k += 4) {
        a0 += w[k] * r[k];
        a1 += w[k + 1] * r[k + 1];
        a2 += w[k + 2] * r[k + 2];
        a3 += w[k + 3] * r[k + 3];
      }
      a0 += w[32] * r[32];
      vp[e] = b + ((a0 + a1) + (a2 + a3));
    }
    dst[g] = v;                       // 16B store, own row -> own lines
  }
}

// ============================================================
// Kernel B (precomputed path): sequential scan, 1 block, 132 threads.
//   thread 4u+p computes gate row j = p*HD+u  (p: 0=i 1=f 2=g 3=o)
//   h double-buffered in LDS, statically alternating (unroll 4)
//   one LGKM-only barrier per step; xp float4 loads stay in flight
//   W_hh1 row PINNED in VGPRs (see pin())
// ============================================================
__global__ void __launch_bounds__(G4, 1)
lstm_scan_pre(const float* __restrict__ xpt,
              const float* __restrict__ W_hh1,
              const float* __restrict__ W_ih2,
              const float* __restrict__ b_ih2,
              const float* __restrict__ b_hh2,
              float* __restrict__ out) {
  __shared__ __align__(16) float hbuf[2][36];  // 144B rows, 16B aligned

  const int tid = threadIdx.x;  // 0..131
  const int u = tid >> 2;       // hidden unit 0..32
  const int p = tid & 3;        // gate part
  const int j = p * HD + u;     // gate row

  float whh[HD];
#pragma unroll
  for (int k = 0; k < HD; ++k) whh[k] = W_hh1[j * HD + k];
#pragma unroll
  for (int k = 0; k < HD; ++k) pin(whh[k]);  // force VGPR residency

  if (tid < HD) {
    hbuf[0][tid] = 0.f;
    hbuf[1][tid] = 0.f;
  }

  // 3-deep float4 pipeline over this thread's private xp row
  const float* xrow = xpt + (size_t)j * TPAD;
  float4 q0 = *reinterpret_cast<const float4*>(xrow + 0);
  float4 q1 = *reinterpret_cast<const float4*>(xrow + 4);
  float4 q2 = *reinterpret_cast<const float4*>(xrow + 8);
  __syncthreads();  // hbuf init visible (one-time full drain is fine)

  float c = 0.f;

#define STEP(XV, RB, WB)                                                   \
  do {                                                                     \
    const float4* h4 = reinterpret_cast<const float4*>(hbuf[RB]);          \
    float a0 = 0.f, a1 = 0.f, a2 = 0.f, a3 = 0.f;                          \
    _Pragma("unroll")                                                      \
    for (int q = 0; q < 8; ++q) {                                          \
      const float4 hq = h4[q];                                             \
      a0 += whh[4 * q] * hq.x;                                             \
      a1 += whh[4 * q + 1] * hq.y;                                         \
      a2 += whh[4 * q + 2] * hq.z;                                         \
      a3 += whh[4 * q + 3] * hq.w;                                         \
    }                                                                      \
    a0 += whh[32] * hbuf[RB][32];                                          \
    const float gate = (XV) + ((a0 + a1) + (a2 + a3));                     \
    const float v = (p == 2) ? tanh_fast(gate) : sigm(gate);               \
    const float iv = qbcast<0x00>(v);                                      \
    const float fv = qbcast<0x55>(v);                                      \
    const float gv = qbcast<0xAA>(v);                                      \
    const float ov = qbcast<0xFF>(v);                                      \
    c = fv * c + iv * gv;                                                  \
    const float hv = ov * tanh_fast(c);                                    \
    if (p == 0) hbuf[WB][u] = hv;                                          \
    LGKM_BARRIER();                                                        \
  } while (0)

  for (int g = 0; g < TLEN / 4; ++g) {  // 25000 groups of 4 steps
    // prefetch for group g+3 (12 steps ahead); stays in flight across barriers
    const float4 qn = *reinterpret_cast<const float4*>(xrow + 4 * g + 12);
    STEP(q0.x, 0, 1);
    STEP(q0.y, 1, 0);
    STEP(q0.z, 0, 1);
    STEP(q0.w, 1, 0);
    q0 = q1; q1 = q2; q2 = qn;
  }
#undef STEP
  // TLEN % 4 == 0 -> final h lives in hbuf[0]

  // ---- decode: 20 steps, lstm2 has no carried state (h=c=0 each step) ----
  float w2[HD];
#pragma unroll
  for (int k = 0; k < HD; ++k) w2[k] = W_ih2[j * HD + k];
  const float b2v = b_ih2[j] + b_hh2[j];

  int cur = 0;
  for (int s = 0; s < NPRED; ++s) {
    const float* xs = hbuf[cur];
    float a0 = 0.f, a1 = 0.f, a2 = 0.f, a3 = 0.f;
#pragma unroll
    for (int k = 0; k < 32; k += 4) {
      a0 += w2[k] * xs[k];
      a1 += w2[k + 1] * xs[k + 1];
      a2 += w2[k + 2] * xs[k + 2];
      a3 += w2[k + 3] * xs[k + 3];
    }
    a0 += w2[32] * xs[32];
    const float gate = b2v + ((a0 + a1) + (a2 + a3));
    const float v = (p == 2) ? tanh_fast(gate) : sigm(gate);
    const float iv = qbcast<0x00>(v);
    const float gv = qbcast<0xAA>(v);
    const float ov = qbcast<0xFF>(v);
    const float c2 = iv * gv;
    const float h2 = ov * tanh_fast(c2);
    if (p == 0) {
      hbuf[cur ^ 1][u] = h2;
      out[s * HD + u] = h2;
    }
    cur ^= 1;
    __syncthreads();
  }
}

// ============================================================
// Fallback (no workspace): fused input projection.
// ============================================================
__global__ void __launch_bounds__(G4, 1)
lstm_scan_fused(const float* __restrict__ mvts,
                const float* __restrict__ W_ih1,
                const float* __restrict__ W_hh1,
                const float* __restrict__ b_ih1,
                const float* __restrict__ b_hh1,
                const float* __restrict__ W_ih2,
                const float* __restrict__ b_ih2,
                const float* __restrict__ b_hh2,
                float* __restrict__ out) {
  __shared__ __align__(16) float hbuf[2][36];
  __shared__ __align__(16) float4 mt4[2][CH * HD / 4];

  const int tid = threadIdx.x;
  const int u = tid >> 2;
  const int p = tid & 3;
  const int j = p * HD + u;

  float whh[HD], wih[HD];
#pragma unroll
  for (int k = 0; k < HD; ++k) whh[k] = W_hh1[j * HD + k];
#pragma unroll
  for (int k = 0; k < HD; ++k) wih[k] = W_ih1[j * HD + k];
#pragma unroll
  for (int k = 0; k < HD; ++k) { pin(whh[k]); pin(wih[k]); }
  const float bv = b_ih1[j] + b_hh1[j];

  if (tid < HD) {
    hbuf[0][tid] = 0.f;
    hbuf[1][tid] = 0.f;
  }
  mt4[0][tid] = reinterpret_cast<const float4*>(mvts)[tid];
  __syncthreads();

  float c = 0.f;
  int cur = 0;
  float4 pfreg;
  for (int t = 0; t < TLEN; ++t) {
    const int tt = t & (CH - 1);
    const int chn = (t >> 4) + 1;
    if (tt == 0 && chn < NCH)
      pfreg = reinterpret_cast<const float4*>(mvts + (size_t)chn * CH * HD)[tid];
    const float* r = reinterpret_cast<const float*>(mt4[(t >> 4) & 1]) + tt * HD;
    float a0 = 0.f, a1 = 0.f, a2 = 0.f, a3 = 0.f;
#pragma unroll
    for (int k = 0; k < 32; k += 4) {
      a0 += wih[k] * r[k];
      a1 += wih[k + 1] * r[k + 1];
      a2 += wih[k + 2] * r[k + 2];
      a3 += wih[k + 3] * r[k + 3];
    }
    a0 += wih[32] * r[32];
    float xv = bv + ((a0 + a1) + (a2 + a3));
    if (tt == CH - 1 && chn < NCH) mt4[chn & 1][tid] = pfreg;

    const float* hs = hbuf[cur];
    float b0 = 0.f, b1 = 0.f, b2 = 0.f, b3 = 0.f;
#pragma unroll
    for (int k = 0; k < 32; k += 4) {
      b0 += whh[k] * hs[k];
      b1 += whh[k + 1] * hs[k + 1];
      b2 += whh[k + 2] * hs[k + 2];
      b3 += whh[k + 3] * hs[k + 3];
    }
    b0 += whh[32] * hs[32];
    const float gate = xv + ((b0 + b1) + (b2 + b3));
    const float v = (p == 2) ? tanh_fast(gate) : sigm(gate);
    const float iv = qbcast<0x00>(v);
    const float fv = qbcast<0x55>(v);
    const float gv = qbcast<0xAA>(v);
    const float ov = qbcast<0xFF>(v);
    c = fv * c + iv * gv;
    const float hv = ov * tanh_fast(c);
    if (p == 0) hbuf[cur ^ 1][u] = hv;
    cur ^= 1;
    __syncthreads();
  }

  float w2[HD];
#pragma unroll
  for (int k = 0; k < HD; ++k) w2[k] = W_ih2[j * HD + k];
  const float b2v = b_ih2[j] + b_hh2[j];

  for (int s = 0; s < NPRED; ++s) {
    const float* xs = hbuf[cur];
    float a0 = 0.f, a1 = 0.f, a2 = 0.f, a3 = 0.f;
#pragma unroll
    for (int k = 0; k < 32; k += 4) {
      a0 += w2[k] * xs[k];
      a1 += w2[k + 1] * xs[k + 1];
      a2 += w2[k + 2] * xs[k + 2];
      a3 += w2[k + 3] * xs[k + 3];
    }
    a0 += w2[32] * xs[32];
    const float gate = b2v + ((a0 + a1) + (a2 + a3));
    const float v = (p == 2) ? tanh_fast(gate) : sigm(gate);
    const float iv = qbcast<0x00>(v);
    const float gv = qbcast<0xAA>(v);
    const float ov = qbcast<0xFF>(v);
    const float c2 = iv * gv;
    const float h2 = ov * tanh_fast(c2);
    if (p == 0) {
      hbuf[cur ^ 1][u] = h2;
      out[s * HD + u] = h2;
    }
    cur ^= 1;
    __syncthreads();
  }
}

// ============================================================
extern "C" void kernel_launch(void* const* d_in, const int* in_sizes, int n_in,
                              void* d_out, int out_size, void* d_ws, size_t ws_size,
                              hipStream_t stream) {
  const float* mvts  = (const float*)d_in[0];
  const float* W_ih1 = (const float*)d_in[1];
  const float* W_hh1 = (const float*)d_in[2];
  const float* b_ih1 = (const float*)d_in[3];
  const float* b_hh1 = (const float*)d_in[4];
  const float* W_ih2 = (const float*)d_in[5];
  // d_in[6] = W_hh2: unused (decode always starts from h=c=0)
  const float* b_ih2 = (const float*)d_in[7];
  const float* b_hh2 = (const float*)d_in[8];
  float* out = (float*)d_out;

  const size_t need = (size_t)G4 * TPAD * sizeof(float);  // ~52.8 MB
  if (ws_size >= need) {
    float* xpt = (float*)d_ws;
    xproj_kernel<<<NCH, G4, 0, stream>>>(mvts, W_ih1, b_ih1, b_hh1, xpt);
    lstm_scan_pre<<<1, G4, 0, stream>>>(xpt, W_hh1, W_ih2, b_ih2, b_hh2, out);
  } else {
    lstm_scan_fused<<<1, G4, 0, stream>>>(mvts, W_ih1, W_hh1, b_ih1, b_hh1,
                                          W_ih2, b_ih2, b_hh2, out);
  }
}